// Round 2
// baseline (156.510 us; speedup 1.0000x reference)
//
#include <hip/hip_runtime.h>

#define BROWS 8192
#define TLEN  1024

// One wave (64 lanes) per row; 4 rows per 256-thread block; grid = 2048.
// Each lane owns 16 tokens (4 iterations x int4/float4), all loads issued
// up-front for maximum memory-level parallelism. All reductions are
// wave-local shuffles — no LDS, no barriers.
__global__ __launch_bounds__(256) void row_reduce_kernel(
    const int*   __restrict__ seq,
    const float* __restrict__ logp,
    const float* __restrict__ value,
    const float* __restrict__ reward,
    double*      __restrict__ row_sum,
    double*      __restrict__ row_cnt)
{
    const int row  = blockIdx.x * 4 + (threadIdx.x >> 6);
    const int lane = threadIdx.x & 63;

    const size_t rowoff = (size_t)row * TLEN;
    const int4*   s4 = (const int4*)  (seq    + rowoff);
    const float4* l4 = (const float4*)(logp   + rowoff);
    const float4* v4 = (const float4*)(value  + rowoff);
    const float4* r4 = (const float4*)(reward + rowoff);

    int4   s[4];
    float4 l[4], v[4], r[4];
    #pragma unroll
    for (int k = 0; k < 4; ++k) {
        const int idx = k * 64 + lane;   // coalesced: lane i -> consecutive 16B
        s[k] = s4[idx];
        l[k] = l4[idx];
        v[k] = v4[idx];
        r[k] = r4[idx];
    }

    // First-zero index in this lane's 16 tokens (TLEN = none).
    // Descending k, then .w->.x: each overwrite has a strictly smaller index,
    // so the final value is the minimum zero index.
    int fz = TLEN;
    #pragma unroll
    for (int k = 3; k >= 0; --k) {
        const int base = k * 256 + lane * 4;
        if (s[k].w == 0) fz = base + 3;
        if (s[k].z == 0) fz = base + 2;
        if (s[k].y == 0) fz = base + 1;
        if (s[k].x == 0) fz = base + 0;
    }

    // Wave-wide min, butterfly so every lane ends with the row minimum.
    #pragma unroll
    for (int off = 32; off > 0; off >>= 1)
        fz = min(fz, __shfl_xor(fz, off, 64));

    // mask[t] = 1 iff t <= fz  (mask[0]=1 always; t>0 valid iff no zero in
    // tokens [0..t-1]).  Accumulate -logp*(reward-value) in double.
    double acc = 0.0;
    #pragma unroll
    for (int k = 0; k < 4; ++k) {
        const int base = k * 256 + lane * 4;
        if (base + 0 <= fz) acc += (double)(-l[k].x * (r[k].x - v[k].x));
        if (base + 1 <= fz) acc += (double)(-l[k].y * (r[k].y - v[k].y));
        if (base + 2 <= fz) acc += (double)(-l[k].z * (r[k].z - v[k].z));
        if (base + 3 <= fz) acc += (double)(-l[k].w * (r[k].w - v[k].w));
    }

    // Wave-wide double sum.
    #pragma unroll
    for (int off = 32; off > 0; off >>= 1)
        acc += __shfl_xor(acc, off, 64);

    if (lane == 0) {
        row_sum[row] = acc;
        row_cnt[row] = (double)min(fz + 1, TLEN);
    }
}

// Single block: reduce 8192 row partials deterministically, write scalar.
__global__ __launch_bounds__(256) void final_reduce_kernel(
    const double* __restrict__ row_sum,
    const double* __restrict__ row_cnt,
    float*        __restrict__ out)
{
    const int tid  = threadIdx.x;
    const int lane = tid & 63;
    const int wave = tid >> 6;

    double s = 0.0, c = 0.0;
    for (int i = tid; i < BROWS; i += 256) {
        s += row_sum[i];
        c += row_cnt[i];
    }
    #pragma unroll
    for (int off = 32; off > 0; off >>= 1) {
        s += __shfl_xor(s, off, 64);
        c += __shfl_xor(c, off, 64);
    }
    __shared__ double ls[4], lc[4];
    if (lane == 0) { ls[wave] = s; lc[wave] = c; }
    __syncthreads();
    if (tid == 0) {
        double ts = ls[0] + ls[1] + ls[2] + ls[3];
        double tc = lc[0] + lc[1] + lc[2] + lc[3];
        out[0] = (float)(ts / tc);
    }
}

extern "C" void kernel_launch(void* const* d_in, const int* in_sizes, int n_in,
                              void* d_out, int out_size, void* d_ws, size_t ws_size,
                              hipStream_t stream) {
    const int*   seq    = (const int*)  d_in[0];
    const float* logp   = (const float*)d_in[1];
    const float* value  = (const float*)d_in[2];
    const float* reward = (const float*)d_in[3];
    float* out = (float*)d_out;

    double* row_sum = (double*)d_ws;            // 8192 * 8 B
    double* row_cnt = row_sum + BROWS;          // 8192 * 8 B  (128 KB total)

    row_reduce_kernel<<<BROWS / 4, 256, 0, stream>>>(seq, logp, value, reward,
                                                     row_sum, row_cnt);
    final_reduce_kernel<<<1, 256, 0, stream>>>(row_sum, row_cnt, out);
}

// Round 3
// 155.983 us; speedup vs baseline: 1.0034x; 1.0034x over previous
//
#include <hip/hip_runtime.h>

#define BROWS 8192
#define TLEN  1024
#define NBLK  2048      // kernel B grid
#define RPB   4         // rows per block in kernel B (NBLK*RPB == BROWS)

// ---------------- Kernel A: first-zero index per row (reads seq only) -------
// One wave per row, 4 rows per 256-thread block, grid = BROWS/4.
__global__ __launch_bounds__(256) void fz_kernel(
    const int* __restrict__ seq,
    int*       __restrict__ fz_out)
{
    const int row  = blockIdx.x * 4 + (threadIdx.x >> 6);
    const int lane = threadIdx.x & 63;

    const int4* s4 = (const int4*)(seq + (size_t)row * TLEN);
    int4 s[4];
    #pragma unroll
    for (int k = 0; k < 4; ++k)
        s[k] = s4[k * 64 + lane];

    // First-zero among this lane's 16 tokens (TLEN = none). Descending order
    // so the last overwrite is the smallest index.
    int fz = TLEN;
    #pragma unroll
    for (int k = 3; k >= 0; --k) {
        const int base = k * 256 + lane * 4;
        if (s[k].w == 0) fz = base + 3;
        if (s[k].z == 0) fz = base + 2;
        if (s[k].y == 0) fz = base + 1;
        if (s[k].x == 0) fz = base + 0;
    }
    #pragma unroll
    for (int off = 32; off > 0; off >>= 1)
        fz = min(fz, __shfl_xor(fz, off, 64));

    if (lane == 0) fz_out[row] = fz;
}

// ---------------- Kernel B: pure streaming masked accumulate ----------------
// Block b handles rows {b, b+NBLK, b+2*NBLK, b+3*NBLK}; within a row, thread
// tid owns float4 index tid (256 float4 = 1024 tokens). No seq reads, no
// cross-lane ops in the hot path — one reduce per block at the very end.
__global__ __launch_bounds__(256) void sum_kernel(
    const float* __restrict__ logp,
    const float* __restrict__ value,
    const float* __restrict__ reward,
    const int*   __restrict__ fz_in,
    double*      __restrict__ blk_sum)
{
    const int tid = threadIdx.x;

    float4 l[RPB], v[RPB], r[RPB];
    int    fz[RPB];
    #pragma unroll
    for (int k = 0; k < RPB; ++k) {
        const int    row = blockIdx.x + k * NBLK;
        const size_t off = (size_t)row * TLEN;
        l[k]  = ((const float4*)(logp   + off))[tid];
        v[k]  = ((const float4*)(value  + off))[tid];
        r[k]  = ((const float4*)(reward + off))[tid];
        fz[k] = fz_in[row];           // block-uniform
    }

    const int t0 = tid * 4;
    double acc = 0.0;
    #pragma unroll
    for (int k = 0; k < RPB; ++k) {
        // mask[t] = 1 iff t <= fz (verified absmax 0.0 in prior rounds)
        if (t0 + 0 <= fz[k]) acc += (double)(-l[k].x * (r[k].x - v[k].x));
        if (t0 + 1 <= fz[k]) acc += (double)(-l[k].y * (r[k].y - v[k].y));
        if (t0 + 2 <= fz[k]) acc += (double)(-l[k].z * (r[k].z - v[k].z));
        if (t0 + 3 <= fz[k]) acc += (double)(-l[k].w * (r[k].w - v[k].w));
    }

    #pragma unroll
    for (int off = 32; off > 0; off >>= 1)
        acc += __shfl_xor(acc, off, 64);

    __shared__ double ls[4];
    if ((tid & 63) == 0) ls[tid >> 6] = acc;
    __syncthreads();
    if (tid == 0)
        blk_sum[blockIdx.x] = ls[0] + ls[1] + ls[2] + ls[3];
}

// ---------------- Kernel C: final scalar -----------------------------------
__global__ __launch_bounds__(256) void final_kernel(
    const double* __restrict__ blk_sum,
    const int*    __restrict__ fz_in,
    float*        __restrict__ out)
{
    const int tid  = threadIdx.x;
    const int lane = tid & 63;
    const int wave = tid >> 6;

    double s = 0.0, c = 0.0;
    for (int i = tid; i < NBLK; i += 256)
        s += blk_sum[i];
    for (int i = tid; i < BROWS; i += 256)
        c += (double)min(fz_in[i] + 1, TLEN);

    #pragma unroll
    for (int off = 32; off > 0; off >>= 1) {
        s += __shfl_xor(s, off, 64);
        c += __shfl_xor(c, off, 64);
    }
    __shared__ double ls[4], lc[4];
    if (lane == 0) { ls[wave] = s; lc[wave] = c; }
    __syncthreads();
    if (tid == 0) {
        double ts = ls[0] + ls[1] + ls[2] + ls[3];
        double tc = lc[0] + lc[1] + lc[2] + lc[3];
        out[0] = (float)(ts / tc);
    }
}

extern "C" void kernel_launch(void* const* d_in, const int* in_sizes, int n_in,
                              void* d_out, int out_size, void* d_ws, size_t ws_size,
                              hipStream_t stream) {
    const int*   seq    = (const int*)  d_in[0];
    const float* logp   = (const float*)d_in[1];
    const float* value  = (const float*)d_in[2];
    const float* reward = (const float*)d_in[3];
    float* out = (float*)d_out;

    int*    fz      = (int*)d_ws;                     // 8192 * 4 B = 32 KB
    double* blk_sum = (double*)((char*)d_ws + 65536); // 2048 * 8 B = 16 KB

    fz_kernel   <<<BROWS / 4, 256, 0, stream>>>(seq, fz);
    sum_kernel  <<<NBLK,      256, 0, stream>>>(logp, value, reward, fz, blk_sum);
    final_kernel<<<1,         256, 0, stream>>>(blk_sum, fz, out);
}